// Round 4
// baseline (1103.687 us; speedup 1.0000x reference)
//
#include <hip/hip_runtime.h>
#include <stdint.h>

// ============================================================================
// LeapfrogIntegrator — round 5: friction restructured to 4-rows x 4-dims
// per-lane partial tiles (weights read 4x less often), features broadcast
// through a per-wave LDS buffer instead of 640 DS-pipe shfl/broadcast reads.
//
// Integrator layout unchanged: lane(q,c) owns row c's dims [16q,16q+16).
// Friction layout: lane(q,c) accumulates gate for rows 4q..4q+3, dims
// 4c..4c+3, j sequential 0..127 (reference order), then mu is redistributed
// back through LDS (wave-synchronous: no __syncthreads needed).
//
// Numerics: np op-order fp32 v-updates (contract off, IEEE division),
// fp64 x-chain with exact mod-2pi wrap, friction reuse (mu_half of step s
// == mu of step s+1), sigmoid computed exactly as verified kernel
// (sg = 1/(1+exp(-g)); mu = FRIC*sg).
// ============================================================================

#define HDT  0.05f
#define EPS  1e-8f
#define FRIC 0.05f

#define SU   68   // U row stride (words)
#define SWT  68   // Wf^T row stride
#define SWR  20   // W^T (dims x ranks) row stride
#define FSTR 132  // per-wave feature buffer row stride (words)

__device__ __forceinline__ float bf1(uint16_t v){ return __builtin_bit_cast(float,(uint32_t)v<<16); }
__device__ __forceinline__ uint16_t rb16(float f){            // RNE bf16 pack
  uint32_t u=__builtin_bit_cast(uint32_t,f);
  return (uint16_t)((u + 0x7fffu + ((u>>16)&1u))>>16);
}
__device__ __forceinline__ float ldw(const void* p,int i,bool isbf){
  return isbf ? bf1(((const uint16_t*)p)[i]) : ((const float*)p)[i];
}

__device__ __forceinline__ void ld16(const void* p, size_t base, bool isbf, float* out){
  if(isbf){
    const uint16_t* pp=(const uint16_t*)p+base;
    uint4 a=*(const uint4*)pp, b=*(const uint4*)(pp+8);
    uint32_t w[8]={a.x,a.y,a.z,a.w,b.x,b.y,b.z,b.w};
    #pragma unroll
    for(int k=0;k<8;++k){
      out[2*k  ]=__builtin_bit_cast(float,w[k]<<16);
      out[2*k+1]=__builtin_bit_cast(float,w[k]&0xffff0000u);
    }
  } else {
    const float* pp=(const float*)p+base;
    #pragma unroll
    for(int k=0;k<4;++k){
      float4 t=((const float4*)pp)[k];
      out[4*k]=t.x; out[4*k+1]=t.y; out[4*k+2]=t.z; out[4*k+3]=t.w;
    }
  }
}
__device__ __forceinline__ void st16(void* p, size_t base, bool isbf, const float* in){
  if(isbf){
    uint16_t* pp=(uint16_t*)p+base;
    uint32_t w[8];
    #pragma unroll
    for(int k=0;k<8;++k) w[k]=(uint32_t)rb16(in[2*k]) | ((uint32_t)rb16(in[2*k+1])<<16);
    *(uint4*)pp     = make_uint4(w[0],w[1],w[2],w[3]);
    *(uint4*)(pp+8) = make_uint4(w[4],w[5],w[6],w[7]);
  } else {
    float* pp=(float*)p+base;
    ((float4*)pp)[0]=make_float4(in[0],in[1],in[2],in[3]);
    ((float4*)pp)[1]=make_float4(in[4],in[5],in[6],in[7]);
    ((float4*)pp)[2]=make_float4(in[8],in[9],in[10],in[11]);
    ((float4*)pp)[3]=make_float4(in[12],in[13],in[14],in[15]);
  }
}

__global__ __launch_bounds__(256) void leapfrog(
    const void* __restrict__ xg, const void* __restrict__ vg,
    const void* __restrict__ fg, const void* __restrict__ Ug,
    const void* __restrict__ Wg, const void* __restrict__ Wfg,
    const void* __restrict__ bg, const int* __restrict__ stepsp,
    void* __restrict__ outp, int n_rows, int n_tiles)
{
  __shared__ float sU [16*SU];     // U[r][d]   at r*SU+d
  __shared__ float sWr[64*SWR];    // W^T[d][r] at d*SWR+r
  __shared__ float sWt[128*SWT];   // Wf^T[j][d] at j*SWT+d (j in [0,128))
  __shared__ float sb [64];
  __shared__ float sFeat[4][16*FSTR]; // per-wave: [row][j] features / mu exchange

  const int tid=threadIdx.x, lane=tid&63, wid=tid>>6;
  const int q=lane>>4, c=lane&15;
  float* feat=&sFeat[wid][0];

  // ---- runtime dtype detection on U ----
  bool isbf;
  {
    const uint16_t* u=(const uint16_t*)Ug; int cnt=0;
    #pragma unroll
    for(int i=0;i<32;++i){ float t=fabsf(bf1(u[2*i])); cnt += ((t==0.f)||(t>1e-6f&&t<100.f)) ? 1:0; }
    isbf = (cnt>=24);
  }
  int steps = stepsp[0]; steps = steps<0 ? 0 : (steps>16 ? 16 : steps);

  // ---- stage weights as f32 in LDS ----
  for(int i=tid;i<1024;i+=256){ sU[(i>>6)*SU+(i&63)] = ldw(Ug,i,isbf); }
  for(int i=tid;i<1024;i+=256){ int r=i>>6,d=i&63; sWr[d*SWR+r] = ldw(Wg,i,isbf); }
  for(int i=tid;i<8192;i+=256){ int d=i>>7,j=i&127; sWt[j*SWT+d] = ldw(Wfg,i,isbf); }
  if(tid<64) sb[tid]=ldw(bg,tid,isbf);
  __syncthreads();

  const int tile = blockIdx.x*4 + wid;
  if(tile >= n_tiles) return;

  const size_t base=(size_t)(tile*16+c)*64 + 16*q;

  float vs[16],fs[16],mu[16],vh[16],gm[16],xin[16];
  double x64[16];
  ld16(xg,base,isbf,xin);
  ld16(vg,base,isbf,vs);
  ld16(fg,base,isbf,fs);
  #pragma unroll
  for(int i=0;i<16;++i) x64[i]=(double)xin[i];

  // gamma = ((v @ U^T)^2) @ W, for this thread's 16 dims (unchanged, verified)
  auto christoffel=[&](const float* vv, float* g){
    float a2[16];
    #pragma unroll
    for(int r=0;r<16;++r){
      const float4* up=(const float4*)&sU[r*SU+16*q];
      float4 u0=up[0],u1=up[1],u2=up[2],u3=up[3];
      float t;
      t =       u0.x*vv[0];      t=fmaf(u0.y,vv[1],t);  t=fmaf(u0.z,vv[2],t);  t=fmaf(u0.w,vv[3],t);
      t=fmaf(u1.x,vv[4],t);  t=fmaf(u1.y,vv[5],t);  t=fmaf(u1.z,vv[6],t);  t=fmaf(u1.w,vv[7],t);
      t=fmaf(u2.x,vv[8],t);  t=fmaf(u2.y,vv[9],t);  t=fmaf(u2.z,vv[10],t); t=fmaf(u2.w,vv[11],t);
      t=fmaf(u3.x,vv[12],t); t=fmaf(u3.y,vv[13],t); t=fmaf(u3.z,vv[14],t); t=fmaf(u3.w,vv[15],t);
      t += __shfl_xor(t,16);
      t += __shfl_xor(t,32);
      a2[r]=t*t;
    }
    #pragma unroll
    for(int i=0;i<16;++i){
      const float4* wp=(const float4*)&sWr[(16*q+i)*SWR];
      float4 w0=wp[0],w1=wp[1],w2=wp[2],w3=wp[3];
      float t;
      t =       a2[0]*w0.x;      t=fmaf(a2[1],w0.y,t);  t=fmaf(a2[2],w0.z,t);  t=fmaf(a2[3],w0.w,t);
      t=fmaf(a2[4],w1.x,t);  t=fmaf(a2[5],w1.y,t);  t=fmaf(a2[6],w1.z,t);  t=fmaf(a2[7],w1.w,t);
      t=fmaf(a2[8],w2.x,t);  t=fmaf(a2[9],w2.y,t);  t=fmaf(a2[10],w2.z,t); t=fmaf(a2[11],w2.w,t);
      t=fmaf(a2[12],w3.x,t); t=fmaf(a2[13],w3.y,t); t=fmaf(a2[14],w3.z,t); t=fmaf(a2[15],w3.w,t);
      g[i]=t;
    }
  };

  // mu = FRIC*sigmoid([sin x, cos x] @ Wf^T + b) — restructured.
  // Phase 1: owner lane publishes sin/cos of its 16 dims to feat[row][j].
  // Phase 2: lane (q,c) accumulates gate for rows 4q+r (r=0..3), dims
  //          4c..4c+3, sequentially over j=0..127 (reference order).
  // Phase 3: sigmoid, publish mu, read back in integrator layout.
  // All exchanges are intra-wave through the per-wave feat buffer;
  // s_waitcnt lgkmcnt(0) orders write->read (wave-synchronous, no barrier).
  auto friction=[&](float* m){
    {
      float sn[16],cn[16];
      #pragma unroll
      for(int i=0;i<16;++i){ float xf=(float)x64[i]; sn[i]=__sinf(xf); cn[i]=__cosf(xf); }
      float4* ps=(float4*)&feat[c*FSTR+16*q];
      float4* pc=(float4*)&feat[c*FSTR+64+16*q];
      #pragma unroll
      for(int k=0;k<4;++k){
        ps[k]=make_float4(sn[4*k],sn[4*k+1],sn[4*k+2],sn[4*k+3]);
        pc[k]=make_float4(cn[4*k],cn[4*k+1],cn[4*k+2],cn[4*k+3]);
      }
    }
    asm volatile("s_waitcnt lgkmcnt(0)" ::: "memory");

    float g4[16];   // g4[4*r+dd]: row 4q+r, dim 4c+dd
    {
      float4 b=*(const float4*)&sb[4*c];
      #pragma unroll
      for(int r=0;r<4;++r){ g4[4*r]=b.x; g4[4*r+1]=b.y; g4[4*r+2]=b.z; g4[4*r+3]=b.w; }
    }
    const float* fr0=&feat[(4*q+0)*FSTR];
    const float* fr1=&feat[(4*q+1)*FSTR];
    const float* fr2=&feat[(4*q+2)*FSTR];
    const float* fr3=&feat[(4*q+3)*FSTR];
    #pragma unroll 4
    for(int jb=0;jb<32;++jb){
      const int j0=4*jb;
      float4 f0=*(const float4*)&fr0[j0];
      float4 f1=*(const float4*)&fr1[j0];
      float4 f2=*(const float4*)&fr2[j0];
      float4 f3=*(const float4*)&fr3[j0];
      float4 w0=*(const float4*)&sWt[(j0+0)*SWT+4*c];
      float4 w1=*(const float4*)&sWt[(j0+1)*SWT+4*c];
      float4 w2=*(const float4*)&sWt[(j0+2)*SWT+4*c];
      float4 w3=*(const float4*)&sWt[(j0+3)*SWT+4*c];
      // j0+0
      g4[ 0]=fmaf(f0.x,w0.x,g4[ 0]); g4[ 1]=fmaf(f0.x,w0.y,g4[ 1]); g4[ 2]=fmaf(f0.x,w0.z,g4[ 2]); g4[ 3]=fmaf(f0.x,w0.w,g4[ 3]);
      g4[ 4]=fmaf(f1.x,w0.x,g4[ 4]); g4[ 5]=fmaf(f1.x,w0.y,g4[ 5]); g4[ 6]=fmaf(f1.x,w0.z,g4[ 6]); g4[ 7]=fmaf(f1.x,w0.w,g4[ 7]);
      g4[ 8]=fmaf(f2.x,w0.x,g4[ 8]); g4[ 9]=fmaf(f2.x,w0.y,g4[ 9]); g4[10]=fmaf(f2.x,w0.z,g4[10]); g4[11]=fmaf(f2.x,w0.w,g4[11]);
      g4[12]=fmaf(f3.x,w0.x,g4[12]); g4[13]=fmaf(f3.x,w0.y,g4[13]); g4[14]=fmaf(f3.x,w0.z,g4[14]); g4[15]=fmaf(f3.x,w0.w,g4[15]);
      // j0+1
      g4[ 0]=fmaf(f0.y,w1.x,g4[ 0]); g4[ 1]=fmaf(f0.y,w1.y,g4[ 1]); g4[ 2]=fmaf(f0.y,w1.z,g4[ 2]); g4[ 3]=fmaf(f0.y,w1.w,g4[ 3]);
      g4[ 4]=fmaf(f1.y,w1.x,g4[ 4]); g4[ 5]=fmaf(f1.y,w1.y,g4[ 5]); g4[ 6]=fmaf(f1.y,w1.z,g4[ 6]); g4[ 7]=fmaf(f1.y,w1.w,g4[ 7]);
      g4[ 8]=fmaf(f2.y,w1.x,g4[ 8]); g4[ 9]=fmaf(f2.y,w1.y,g4[ 9]); g4[10]=fmaf(f2.y,w1.z,g4[10]); g4[11]=fmaf(f2.y,w1.w,g4[11]);
      g4[12]=fmaf(f3.y,w1.x,g4[12]); g4[13]=fmaf(f3.y,w1.y,g4[13]); g4[14]=fmaf(f3.y,w1.z,g4[14]); g4[15]=fmaf(f3.y,w1.w,g4[15]);
      // j0+2
      g4[ 0]=fmaf(f0.z,w2.x,g4[ 0]); g4[ 1]=fmaf(f0.z,w2.y,g4[ 1]); g4[ 2]=fmaf(f0.z,w2.z,g4[ 2]); g4[ 3]=fmaf(f0.z,w2.w,g4[ 3]);
      g4[ 4]=fmaf(f1.z,w2.x,g4[ 4]); g4[ 5]=fmaf(f1.z,w2.y,g4[ 5]); g4[ 6]=fmaf(f1.z,w2.z,g4[ 6]); g4[ 7]=fmaf(f1.z,w2.w,g4[ 7]);
      g4[ 8]=fmaf(f2.z,w2.x,g4[ 8]); g4[ 9]=fmaf(f2.z,w2.y,g4[ 9]); g4[10]=fmaf(f2.z,w2.z,g4[10]); g4[11]=fmaf(f2.z,w2.w,g4[11]);
      g4[12]=fmaf(f3.z,w2.x,g4[12]); g4[13]=fmaf(f3.z,w2.y,g4[13]); g4[14]=fmaf(f3.z,w2.z,g4[14]); g4[15]=fmaf(f3.z,w2.w,g4[15]);
      // j0+3
      g4[ 0]=fmaf(f0.w,w3.x,g4[ 0]); g4[ 1]=fmaf(f0.w,w3.y,g4[ 1]); g4[ 2]=fmaf(f0.w,w3.z,g4[ 2]); g4[ 3]=fmaf(f0.w,w3.w,g4[ 3]);
      g4[ 4]=fmaf(f1.w,w3.x,g4[ 4]); g4[ 5]=fmaf(f1.w,w3.y,g4[ 5]); g4[ 6]=fmaf(f1.w,w3.z,g4[ 6]); g4[ 7]=fmaf(f1.w,w3.w,g4[ 7]);
      g4[ 8]=fmaf(f2.w,w3.x,g4[ 8]); g4[ 9]=fmaf(f2.w,w3.y,g4[ 9]); g4[10]=fmaf(f2.w,w3.z,g4[10]); g4[11]=fmaf(f2.w,w3.w,g4[11]);
      g4[12]=fmaf(f3.w,w3.x,g4[12]); g4[13]=fmaf(f3.w,w3.y,g4[13]); g4[14]=fmaf(f3.w,w3.z,g4[14]); g4[15]=fmaf(f3.w,w3.w,g4[15]);
    }
    // sigmoid exactly as verified kernel: sg=1/(1+exp(-g)); mu=FRIC*sg
    #pragma unroll
    for(int r=0;r<4;++r){
      float s0=1.f/(1.f+__expf(-g4[4*r+0]));
      float s1=1.f/(1.f+__expf(-g4[4*r+1]));
      float s2=1.f/(1.f+__expf(-g4[4*r+2]));
      float s3=1.f/(1.f+__expf(-g4[4*r+3]));
      *(float4*)&feat[(4*q+r)*FSTR+4*c]=make_float4(FRIC*s0,FRIC*s1,FRIC*s2,FRIC*s3);
    }
    asm volatile("s_waitcnt lgkmcnt(0)" ::: "memory");
    #pragma unroll
    for(int k=0;k<4;++k){
      float4 t=*(const float4*)&feat[c*FSTR+16*q+4*k];
      m[4*k]=t.x; m[4*k+1]=t.y; m[4*k+2]=t.z; m[4*k+3]=t.w;
    }
  };

  friction(mu);                    // mu(x0); carried across half-steps

  for(int s=0;s<steps;++s){
    christoffel(vs,gm);
    {
      #pragma clang fp contract(off)
      #pragma unroll
      for(int i=0;i<16;++i){
        float t  = HDT*(fs[i]-gm[i]);            // np op order
        float num= vs[i]+t;
        float den= (1.f + HDT*mu[i]) + EPS;
        vh[i]= num/den;                          // IEEE division (no fast-math)
        float p  = 0.1f*vh[i];                   // matches np's f32 product
        double xx = x64[i] + (double)p;
        double n  = __builtin_rint(xx*0.15915494309189535);
        x64[i] = __builtin_fma(-6.283185307179586, n, xx);  // exact mod-2pi
      }
    }
    friction(mu);                  // mu_half == next step's mu (bit-identical)
    christoffel(vh,gm);
    {
      #pragma clang fp contract(off)
      #pragma unroll
      for(int i=0;i<16;++i){
        float t  = HDT*(fs[i]-gm[i]);
        float num= vh[i]+t;
        float den= (1.f + HDT*mu[i]) + EPS;
        vs[i]= num/den;
      }
    }
  }

  float xf[16];
  #pragma unroll
  for(int i=0;i<16;++i) xf[i]=(float)x64[i];

  // outputs: (x, v) concatenated; element offset n_rows*64 for v
  const size_t voff=(size_t)n_rows*64;
  if(isbf){
    uint16_t* o=(uint16_t*)outp;
    st16(o,        base, true, xf);
    st16(o+voff,   base, true, vs);
  } else {
    float* o=(float*)outp;
    st16(o,        base, false, xf);
    st16(o+voff,   base, false, vs);
  }
}

extern "C" void kernel_launch(void* const* d_in, const int* in_sizes, int n_in,
                              void* d_out, int out_size, void* d_ws, size_t ws_size,
                              hipStream_t stream) {
  const int n_rows  = in_sizes[0] / 64;
  const int n_tiles = n_rows / 16;
  const int grid    = (n_tiles + 3) / 4;       // 4 waves/block, 1 tile/wave
  leapfrog<<<dim3(grid), dim3(256), 0, stream>>>(
      d_in[0], d_in[1], d_in[2], d_in[3], d_in[4], d_in[5], d_in[6],
      (const int*)d_in[7], d_out, n_rows, n_tiles);
}